// Round 10
// baseline (230.029 us; speedup 1.0000x reference)
//
#include <hip/hip_runtime.h>
#include <hip/hip_bf16.h>

#define BB 2
#define SS 2048
#define DD 1024
#define HH 16
#define HD 64

typedef __attribute__((ext_vector_type(8))) short bf16x8;
typedef __attribute__((ext_vector_type(4))) float f32x4;

// round-to-nearest-even f32 -> bf16 (inputs finite)
__device__ __forceinline__ unsigned short f2bf(float f) {
  unsigned int u = __float_as_uint(f);
  return (unsigned short)((u + 0x7FFFu + ((u >> 16) & 1u)) >> 16);
}

// 2^x via hardware v_exp_f32
__device__ __forceinline__ float fast_exp2(float x) {
#if __has_builtin(__builtin_amdgcn_exp2f)
  return __builtin_amdgcn_exp2f(x);
#else
  return __expf(x * 0.6931471805599453f);
#endif
}

__device__ __forceinline__ void async_copy16(const unsigned short* gp, unsigned short* lp) {
  __builtin_amdgcn_global_load_lds(
      (const __attribute__((address_space(1))) unsigned int*)gp,
      (__attribute__((address_space(3))) unsigned int*)lp, 16, 0, 0);
}

// ---------------------------------------------------------------------------
// Fused prep: blocks [0,4096) convert x -> bf16; blocks [4096,8192) transpose
// one of the 4 weight matrices (1024 32x32 tiles each) to bf16 [N][K].
// ---------------------------------------------------------------------------
__global__ __launch_bounds__(256) void prep_kernel(
    const float* __restrict__ x, unsigned short* __restrict__ xb,
    const float* __restrict__ W0, unsigned short* __restrict__ T0,
    const float* __restrict__ W1, unsigned short* __restrict__ T1,
    const float* __restrict__ W2, unsigned short* __restrict__ T2,
    const float* __restrict__ W3, unsigned short* __restrict__ T3) {
  const int blk = blockIdx.x;
  const int t = threadIdx.x;
  if (blk < 4096) {
    int i = blk * 1024 + t * 4;
    float4 v = *(const float4*)(x + i);
    ushort4 u;
    u.x = f2bf(v.x); u.y = f2bf(v.y); u.z = f2bf(v.z); u.w = f2bf(v.w);
    *(ushort4*)(xb + i) = u;
    return;
  }
  const int j = blk - 4096;
  const int jw = j >> 10;          // which weight
  const int tb = j & 1023;
  const float* W = jw == 0 ? W0 : (jw == 1 ? W1 : (jw == 2 ? W2 : W3));
  unsigned short* T = jw == 0 ? T0 : (jw == 1 ? T1 : (jw == 2 ? T2 : T3));
  __shared__ float tile[32][33];
  int k0 = (tb & 31) * 32, n0 = (tb >> 5) * 32;
  int c = t & 31, r0 = t >> 5;
#pragma unroll
  for (int i = 0; i < 4; ++i) {
    int r = r0 + i * 8;
    tile[r][c] = W[(size_t)(k0 + r) * DD + n0 + c];
  }
  __syncthreads();
#pragma unroll
  for (int i = 0; i < 4; ++i) {
    int r = r0 + i * 8;
    T[(size_t)(n0 + r) * DD + k0 + c] = f2bf(tile[c][r]);
  }
}

// ---------------------------------------------------------------------------
// bf16 MFMA GEMM core, BK=64 single-buffer (half the barrier drains of BK=32;
// NOT R8's dbuf). LDS holds the 64-K tile as two k-major 32-blocks so the
// fragment ds_read_b128 stride stays 64 B (conflict-free, m97-identical).
// D = A[M,K]@B^T[N,K] + bias.
// STORE=0: fp32 out [M][DD]
// STORE=1: bf16 out [B,H,S,HD], value scaled (Q: 0.125*log2e, K: 1)
// STORE=2: bf16 out [B,H,HD,S] (V transposed), LDS-transposed coalesced store
// ---------------------------------------------------------------------------
template <int STORE>
__device__ __forceinline__ void gemm_core(
    const unsigned short* __restrict__ A, const unsigned short* __restrict__ BT,
    const float* __restrict__ bias, void* __restrict__ outp, float scale,
    int bm, int bn) {
  const int t = threadIdx.x;
  const int w = t >> 6;
  const int l = t & 63;
  const int wm = (w >> 1) * 64;
  const int wn = (w & 1) * 64;

  // layout: [kb][row][32] — element (row, k) at (k>>5)*4096 + row*32 + (k&31)
  __shared__ __align__(16) unsigned short As[128 * 64];
  __shared__ __align__(16) unsigned short Bs[128 * 64];

  f32x4 acc[4][4];
#pragma unroll
  for (int i = 0; i < 4; ++i)
#pragma unroll
    for (int j = 0; j < 4; ++j) acc[i][j] = (f32x4)0.f;

  const int fr = l & 15;
  const int kg = (l >> 4) * 8;

  for (int k0 = 0; k0 < DD; k0 += 64) {
    __syncthreads();
#pragma unroll
    for (int c = 0; c < 4; ++c) {
      int e = (w * 4 + c) * 512 + l * 8;   // index into [2][128][32]
      int kb_s = e >> 12;
      int rem = e & 4095;
      int row = rem >> 5, kk = rem & 31;
      async_copy16(A + (size_t)(bm + row) * DD + k0 + kb_s * 32 + kk,
                   As + (w * 4 + c) * 512);
      async_copy16(BT + (size_t)(bn + row) * DD + k0 + kb_s * 32 + kk,
                   Bs + (w * 4 + c) * 512);
    }
    __syncthreads();

#pragma unroll
    for (int kb = 0; kb < 2; ++kb) {
      bf16x8 af[4], bfr[4];
#pragma unroll
      for (int i = 0; i < 4; ++i)
        af[i] = *(const bf16x8*)(As + kb * 4096 + (wm + i * 16 + fr) * 32 + kg);
#pragma unroll
      for (int j = 0; j < 4; ++j)
        bfr[j] = *(const bf16x8*)(Bs + kb * 4096 + (wn + j * 16 + fr) * 32 + kg);
#pragma unroll
      for (int i = 0; i < 4; ++i)
#pragma unroll
        for (int j = 0; j < 4; ++j)
          acc[i][j] = __builtin_amdgcn_mfma_f32_16x16x32_bf16(af[i], bfr[j], acc[i][j], 0, 0, 0);
    }
  }

  const int col_l = l & 15;
  const int row_l = (l >> 4) * 4;

  if (STORE == 2) {
    // Transpose 128x128 C tile via LDS (4 passes of 32 n-cols), then store
    // VbT[(b*HH+h)*HD+hd][s] with 256 B contiguous runs along s.
    unsigned short* out = (unsigned short*)outp;
    unsigned int* T = (unsigned int*)As;  // 2048 dwords
    const int b_ = bm >> 11;
    const int srow0 = bm & 2047;          // within-batch S offset
#pragma unroll
    for (int p = 0; p < 4; ++p) {
      __syncthreads();  // As free (K-loop done / previous pass read done)
      if ((w & 1) == (p >> 1)) {
        const int jt0 = (p & 1) * 2;
#pragma unroll
        for (int jj = 0; jj < 2; ++jj) {
          int jt = jt0 + jj;
          int n_p = jj * 16 + col_l;          // n within pass [0,32)
          float bv = bias[bn + p * 32 + n_p];
#pragma unroll
          for (int i = 0; i < 4; ++i) {
            int m0 = wm + i * 16 + row_l;     // even
#pragma unroll
            for (int pr = 0; pr < 2; ++pr) {
              unsigned int val =
                  (unsigned int)f2bf(acc[i][jt][2 * pr] + bv) |
                  ((unsigned int)f2bf(acc[i][jt][2 * pr + 1] + bv) << 16);
              int m = m0 + 2 * pr;
              T[n_p * 64 + (((m >> 1)) ^ ((n_p & 7) << 2))] = val;
            }
          }
        }
      }
      __syncthreads();
#pragma unroll
      for (int c = 0; c < 2; ++c) {
        int q = t + c * 256;
        int n_p = q >> 4, cpos = q & 15;
        uint4 v = *(const uint4*)(T + n_p * 64 + ((cpos * 4) ^ ((n_p & 7) << 2)));
        int n_glob = bn + p * 32 + n_p;
        int h_ = n_glob >> 6, hd_ = n_glob & 63;
        *(uint4*)(out + ((size_t)((b_ * HH + h_) * HD + hd_)) * SS + srow0 + cpos * 8) = v;
      }
    }
    return;
  }

#pragma unroll
  for (int i = 0; i < 4; ++i) {
    int m_base = bm + wm + i * 16 + row_l;
#pragma unroll
    for (int j = 0; j < 4; ++j) {
      int n = bn + wn + j * 16 + col_l;
      float bv = bias[n];
      if (STORE == 0) {
        float* out = (float*)outp;
#pragma unroll
        for (int r = 0; r < 4; ++r)
          out[(size_t)(m_base + r) * DD + n] = acc[i][j][r] + bv;
      } else {
        unsigned short* out = (unsigned short*)outp;
        int h_ = n >> 6, hd_ = n & 63;
#pragma unroll
        for (int r = 0; r < 4; ++r) {
          int m = m_base + r;
          int b_ = m >> 11, s_ = m & 2047;
          out[(((size_t)(b_ * HH + h_) * SS) + s_) * HD + hd_] =
              f2bf((acc[i][j][r] + bv) * scale);
        }
      }
    }
  }
}

// Fused QKV projection: grid (24, 32) — x = which/bn (fast), y = bm.
__global__ __launch_bounds__(256) void qkv_gemm_mfma(
    const unsigned short* __restrict__ A,
    const unsigned short* __restrict__ WqT, const unsigned short* __restrict__ WkT,
    const unsigned short* __restrict__ WvT,
    const float* __restrict__ bq, const float* __restrict__ bk,
    const float* __restrict__ bv,
    unsigned short* __restrict__ Qo, unsigned short* __restrict__ Ko,
    unsigned short* __restrict__ VTo) {
  const int bm = blockIdx.y * 128;
  const int which = blockIdx.x >> 3;
  const int bn = (blockIdx.x & 7) * 128;
  if (which == 0)
    gemm_core<1>(A, WqT, bq, (void*)Qo, 0.18033688011112042f, bm, bn);
  else if (which == 1)
    gemm_core<1>(A, WkT, bk, (void*)Ko, 1.0f, bm, bn);
  else
    gemm_core<2>(A, WvT, bv, (void*)VTo, 1.0f, bm, bn);
}

// output projection: grid (8, 32) — x = bn (fast), y = bm
__global__ __launch_bounds__(256) void out_gemm_mfma(
    const unsigned short* __restrict__ A, const unsigned short* __restrict__ WoT,
    const float* __restrict__ bo, float* __restrict__ out) {
  gemm_core<0>(A, WoT, bo, (void*)out, 1.0f, blockIdx.y * 128, blockIdx.x * 128);
}

// ---------------------------------------------------------------------------
// MFMA flash attention v5: KV-split. Grid (B*H, S/128, 2); block z handles
// keys [z*1024, (z+1)*1024). No-running-max softmax => partials are exactly
// additive: block writes unnormalized O (fp32) and l to Opart/Lpart; a
// combine kernel computes (O0+O1)/(l0+l1). 1024 blocks = 4/CU (2x occupancy
// of v4). Q-tile 128 (4 waves x 32 q), dbuf K/V staging.
// ---------------------------------------------------------------------------
__global__ __launch_bounds__(256) void flash_attn_mfma(
    const unsigned short* __restrict__ Q,   // [B,H,S,HD] bf16 (pre-scaled)
    const unsigned short* __restrict__ K,   // [B,H,S,HD] bf16
    const unsigned short* __restrict__ VT,  // [B,H,HD,S] bf16
    float* __restrict__ Opart,              // [2][B,S,D] fp32 unnormalized
    float* __restrict__ Lpart) {            // [2][B,H,S] fp32
  const int bh = blockIdx.x;
  const int qt = blockIdx.y;
  const int z  = blockIdx.z;
  const int b  = bh >> 4;
  const int h  = bh & 15;
  const int t  = threadIdx.x;
  const int w  = t >> 6;   // wave 0..3
  const int l  = t & 63;
  const int g  = l >> 4;   // lane group 0..3
  const int ln = l & 15;   // q index within n-tile

  const unsigned short* Qp = Q + ((size_t)bh * SS + (size_t)qt * 128 + w * 32) * HD;
  const unsigned short* Kp = K + (size_t)bh * SS * HD;
  const unsigned short* Vp = VT + (size_t)bh * HD * SS;

  __shared__ __align__(16) unsigned short Ks[2][64 * 64];  // [key][hd], swizzled
  __shared__ __align__(16) unsigned short Vs[2][64 * 64];  // [hd][key], swizzled

  // Q as B-operand fragments: qf[nt][kb], n=ln, k = kb*32 + g*8 + j
  bf16x8 qf[2][2];
#pragma unroll
  for (int nt = 0; nt < 2; ++nt)
#pragma unroll
    for (int kb = 0; kb < 2; ++kb)
      qf[nt][kb] = *(const bf16x8*)(Qp + (nt * 16 + ln) * HD + kb * 32 + g * 8);

  f32x4 o[2][4];
#pragma unroll
  for (int nt = 0; nt < 2; ++nt)
#pragma unroll
    for (int mt = 0; mt < 4; ++mt) o[nt][mt] = (f32x4)0.f;
  float rs[2] = {0.f, 0.f};

  // P-conversion shuffle constants (C-layout -> B-operand layout)
  const int s0 = ((2 * g) & 3) * 16 + ln;
  const int s1 = ((2 * g + 1) & 3) * 16 + ln;
  const bool hi = (g >> 1) != 0;

  const int kt0 = z * (SS / 128);  // 16 iterations of 64 keys each

  auto stage = [&](int kt, int half) {
#pragma unroll
    for (int j = 0; j < 2; ++j) {
      int c = (w * 2 + j) * 64 + l;
      int row = c >> 3, cc = c & 7;
      int gcc = cc ^ (row & 7);
      async_copy16(Kp + (size_t)(kt * 64 + row) * HD + gcc * 8,
                   &Ks[half][(w * 2 + j) * 512]);
      async_copy16(Vp + (size_t)row * SS + kt * 64 + gcc * 8,
                   &Vs[half][(w * 2 + j) * 512]);
    }
  };

  stage(kt0, 0);
  for (int it = 0; it < SS / 128; ++it) {
    const int half = it & 1;
    __syncthreads();  // drains vmcnt -> buf[half] ready; buf[half^1] free
    if (it + 1 < SS / 128) stage(kt0 + it + 1, half ^ 1);

    // --- S^T = K Q^T : st[nt][mt][r] = S[key = mt*16+4g+r][q = nt*16+ln]
    f32x4 st[2][4];
#pragma unroll
    for (int nt = 0; nt < 2; ++nt)
#pragma unroll
      for (int mt = 0; mt < 4; ++mt) st[nt][mt] = (f32x4)0.f;
#pragma unroll
    for (int kb = 0; kb < 2; ++kb)
#pragma unroll
      for (int mt = 0; mt < 4; ++mt) {
        int row = mt * 16 + ln;
        bf16x8 ka = *(const bf16x8*)(&Ks[half][row * 64 + (((kb * 4 + g) ^ (row & 7)) * 8)]);
        st[0][mt] = __builtin_amdgcn_mfma_f32_16x16x32_bf16(ka, qf[0][kb], st[0][mt], 0, 0, 0);
        st[1][mt] = __builtin_amdgcn_mfma_f32_16x16x32_bf16(ka, qf[1][kb], st[1][mt], 0, 0, 0);
      }

    // --- p = exp2(s'); pack to bf16 (v_perm); rs summed in fp32
    unsigned int pu[2][4][2];
#pragma unroll
    for (int nt = 0; nt < 2; ++nt)
#pragma unroll
      for (int mt = 0; mt < 4; ++mt) {
        float p0 = fast_exp2(st[nt][mt][0]);
        float p1 = fast_exp2(st[nt][mt][1]);
        float p2 = fast_exp2(st[nt][mt][2]);
        float p3 = fast_exp2(st[nt][mt][3]);
        pu[nt][mt][0] = __builtin_amdgcn_perm(__float_as_uint(p1), __float_as_uint(p0),
                                              0x07060302u);  // lo=p0,hi=p1
        pu[nt][mt][1] = __builtin_amdgcn_perm(__float_as_uint(p3), __float_as_uint(p2),
                                              0x07060302u);
        rs[nt] += (p0 + p1) + (p2 + p3);
      }

    // --- O^T += V^T P^T : P^T B-frags via lane shuffles, V^T frags shared
#pragma unroll
    for (int kb = 0; kb < 2; ++kb) {
      bf16x8 pbv[2];
#pragma unroll
      for (int nt = 0; nt < 2; ++nt) {
        unsigned int a0 = __shfl((int)pu[nt][2 * kb][0], s0, 64);
        unsigned int b0 = __shfl((int)pu[nt][2 * kb + 1][0], s0, 64);
        unsigned int a1 = __shfl((int)pu[nt][2 * kb][1], s0, 64);
        unsigned int b1 = __shfl((int)pu[nt][2 * kb + 1][1], s0, 64);
        unsigned int a2 = __shfl((int)pu[nt][2 * kb][0], s1, 64);
        unsigned int b2 = __shfl((int)pu[nt][2 * kb + 1][0], s1, 64);
        unsigned int a3 = __shfl((int)pu[nt][2 * kb][1], s1, 64);
        unsigned int b3 = __shfl((int)pu[nt][2 * kb + 1][1], s1, 64);
        union { unsigned int u[4]; bf16x8 v; } pb;
        pb.u[0] = hi ? b0 : a0;
        pb.u[1] = hi ? b1 : a1;
        pb.u[2] = hi ? b2 : a2;
        pb.u[3] = hi ? b3 : a3;
        pbv[nt] = pb.v;
      }
#pragma unroll
      for (int mt = 0; mt < 4; ++mt) {
        int row = mt * 16 + ln;
        bf16x8 va = *(const bf16x8*)(&Vs[half][row * 64 + (((kb * 4 + g) ^ (row & 7)) * 8)]);
        o[0][mt] = __builtin_amdgcn_mfma_f32_16x16x32_bf16(va, pbv[0], o[0][mt], 0, 0, 0);
        o[1][mt] = __builtin_amdgcn_mfma_f32_16x16x32_bf16(va, pbv[1], o[1][mt], 0, 0, 0);
      }
    }
  }

  // --- epilogue: store unnormalized fp32 partials + per-q l
  const size_t ELEMS = (size_t)BB * SS * DD;
#pragma unroll
  for (int nt = 0; nt < 2; ++nt) {
    float lsum = rs[nt];
    lsum += __shfl_xor(lsum, 16, 64);
    lsum += __shfl_xor(lsum, 32, 64);
    int srow = qt * 128 + w * 32 + nt * 16 + ln;
    float* ob = Opart + z * ELEMS + ((size_t)(b * SS + srow)) * DD + h * HD;
#pragma unroll
    for (int mt = 0; mt < 4; ++mt)
      *(f32x4*)(ob + mt * 16 + 4 * g) = o[nt][mt];
    if (g == 0)
      Lpart[z * (BB * HH * SS) + (b * HH + h) * SS + srow] = lsum;
  }
}

// ---------------------------------------------------------------------------
// Combine: ctx_bf16 = (O0 + O1) / (L0 + L1). grid 4096 x 256 thr, float4/thr.
// ---------------------------------------------------------------------------
__global__ __launch_bounds__(256) void combine_kernel(
    const float* __restrict__ Opart, const float* __restrict__ Lpart,
    unsigned short* __restrict__ ctx) {
  const size_t ELEMS = (size_t)BB * SS * DD;
  int idx = (blockIdx.x * 256 + threadIdx.x) * 4;
  float4 a = *(const float4*)(Opart + idx);
  float4 c = *(const float4*)(Opart + ELEMS + idx);
  int sg = idx >> 10;          // global row (b*SS+s)
  int d  = idx & 1023;
  int b = sg >> 11, s = sg & 2047;
  int h = d >> 6;
  int li = (b * HH + h) * SS + s;
  float inv = 1.f / (Lpart[li] + Lpart[BB * HH * SS + li]);
  ushort4 u;
  u.x = f2bf((a.x + c.x) * inv);
  u.y = f2bf((a.y + c.y) * inv);
  u.z = f2bf((a.z + c.z) * inv);
  u.w = f2bf((a.w + c.w) * inv);
  *(ushort4*)(ctx + idx) = u;
}

// ---------------------------------------------------------------------------
extern "C" void kernel_launch(void* const* d_in, const int* in_sizes, int n_in,
                              void* d_out, int out_size, void* d_ws, size_t ws_size,
                              hipStream_t stream) {
  const float* x  = (const float*)d_in[0];
  const float* Wq = (const float*)d_in[1];
  const float* bq = (const float*)d_in[2];
  const float* Wk = (const float*)d_in[3];
  const float* bk = (const float*)d_in[4];
  const float* Wv = (const float*)d_in[5];
  const float* bv = (const float*)d_in[6];
  const float* Wo = (const float*)d_in[7];
  const float* bo = (const float*)d_in[8];
  float* out = (float*)d_out;

  const size_t ELEMS = (size_t)BB * SS * DD;  // 4,194,304
  char* ws = (char*)d_ws;
  unsigned short* xb   = (unsigned short*)ws;  ws += ELEMS * 2;
  unsigned short* WqT  = (unsigned short*)ws;  ws += (size_t)DD * DD * 2;
  unsigned short* WkT  = (unsigned short*)ws;  ws += (size_t)DD * DD * 2;
  unsigned short* WvT  = (unsigned short*)ws;  ws += (size_t)DD * DD * 2;
  unsigned short* WoT  = (unsigned short*)ws;  ws += (size_t)DD * DD * 2;
  unsigned short* Qb   = (unsigned short*)ws;  ws += ELEMS * 2;
  unsigned short* Kb   = (unsigned short*)ws;  ws += ELEMS * 2;
  unsigned short* VbT  = (unsigned short*)ws;  ws += ELEMS * 2;
  unsigned short* ctxb = (unsigned short*)ws;  ws += ELEMS * 2;
  float* Opart = (float*)ws;                   ws += 2 * ELEMS * 4;       // 32 MB
  float* Lpart = (float*)ws;                   ws += 2 * (size_t)BB * HH * SS * 4;

  // fused prep: x->bf16 (4096 blocks) + 4 weight transposes (4096 blocks)
  prep_kernel<<<8192, 256, 0, stream>>>(x, xb, Wq, WqT, Wk, WkT, Wv, WvT, Wo, WoT);

  dim3 qkv_grid(3 * DD / 128, BB * SS / 128);  // (24, 32)
  qkv_gemm_mfma<<<qkv_grid, 256, 0, stream>>>(xb, WqT, WkT, WvT, bq, bk, bv,
                                              Qb, Kb, VbT);

  dim3 attn_grid(BB * HH, SS / 128, 2);        // (32, 16, 2) = 1024 blocks
  flash_attn_mfma<<<attn_grid, 256, 0, stream>>>(Qb, Kb, VbT, Opart, Lpart);

  combine_kernel<<<ELEMS / 1024, 256, 0, stream>>>(Opart, Lpart, ctxb);

  dim3 out_grid(DD / 128, BB * SS / 128);      // (8, 32)
  out_gemm_mfma<<<out_grid, 256, 0, stream>>>(ctxb, WoT, bo, out);
}

// Round 11
// 216.824 us; speedup vs baseline: 1.0609x; 1.0609x over previous
//
#include <hip/hip_runtime.h>
#include <hip/hip_bf16.h>

#define BB 2
#define SS 2048
#define DD 1024
#define HH 16
#define HD 64

typedef __attribute__((ext_vector_type(8))) short bf16x8;
typedef __attribute__((ext_vector_type(4))) float f32x4;

// round-to-nearest-even f32 -> bf16 (inputs finite)
__device__ __forceinline__ unsigned short f2bf(float f) {
  unsigned int u = __float_as_uint(f);
  return (unsigned short)((u + 0x7FFFu + ((u >> 16) & 1u)) >> 16);
}

// 2^x via hardware v_exp_f32
__device__ __forceinline__ float fast_exp2(float x) {
#if __has_builtin(__builtin_amdgcn_exp2f)
  return __builtin_amdgcn_exp2f(x);
#else
  return __expf(x * 0.6931471805599453f);
#endif
}

__device__ __forceinline__ void async_copy16(const unsigned short* gp, unsigned short* lp) {
  __builtin_amdgcn_global_load_lds(
      (const __attribute__((address_space(1))) unsigned int*)gp,
      (__attribute__((address_space(3))) unsigned int*)lp, 16, 0, 0);
}

// ---------------------------------------------------------------------------
// Fused prep: blocks [0,4096) convert x -> bf16; blocks [4096,8192) transpose
// one of the 4 weight matrices (1024 32x32 tiles each) to bf16 [N][K].
// ---------------------------------------------------------------------------
__global__ __launch_bounds__(256) void prep_kernel(
    const float* __restrict__ x, unsigned short* __restrict__ xb,
    const float* __restrict__ W0, unsigned short* __restrict__ T0,
    const float* __restrict__ W1, unsigned short* __restrict__ T1,
    const float* __restrict__ W2, unsigned short* __restrict__ T2,
    const float* __restrict__ W3, unsigned short* __restrict__ T3) {
  const int blk = blockIdx.x;
  const int t = threadIdx.x;
  if (blk < 4096) {
    int i = blk * 1024 + t * 4;
    float4 v = *(const float4*)(x + i);
    ushort4 u;
    u.x = f2bf(v.x); u.y = f2bf(v.y); u.z = f2bf(v.z); u.w = f2bf(v.w);
    *(ushort4*)(xb + i) = u;
    return;
  }
  const int j = blk - 4096;
  const int jw = j >> 10;          // which weight
  const int tb = j & 1023;
  const float* W = jw == 0 ? W0 : (jw == 1 ? W1 : (jw == 2 ? W2 : W3));
  unsigned short* T = jw == 0 ? T0 : (jw == 1 ? T1 : (jw == 2 ? T2 : T3));
  __shared__ float tile[32][33];
  int k0 = (tb & 31) * 32, n0 = (tb >> 5) * 32;
  int c = t & 31, r0 = t >> 5;
#pragma unroll
  for (int i = 0; i < 4; ++i) {
    int r = r0 + i * 8;
    tile[r][c] = W[(size_t)(k0 + r) * DD + n0 + c];
  }
  __syncthreads();
#pragma unroll
  for (int i = 0; i < 4; ++i) {
    int r = r0 + i * 8;
    T[(size_t)(n0 + r) * DD + k0 + c] = f2bf(tile[c][r]);
  }
}

// ---------------------------------------------------------------------------
// bf16 MFMA GEMM core (m97 single-buffer, BK=32): D = A[M,K]@B^T[N,K] + bias
// STORE=0: fp32 out [M][DD]
// STORE=1: bf16 out [B,H,S,HD], value scaled (Q: 0.125*log2e, K: 1)
// STORE=2: bf16 out [B,H,HD,S] (V transposed), LDS-transposed coalesced store
// ---------------------------------------------------------------------------
template <int STORE>
__device__ __forceinline__ void gemm_core(
    const unsigned short* __restrict__ A, const unsigned short* __restrict__ BT,
    const float* __restrict__ bias, void* __restrict__ outp, float scale,
    int bm, int bn) {
  const int t = threadIdx.x;
  const int w = t >> 6;
  const int l = t & 63;
  const int wm = (w >> 1) * 64;
  const int wn = (w & 1) * 64;

  __shared__ __align__(16) unsigned short As[128 * 32];
  __shared__ __align__(16) unsigned short Bs[128 * 32];

  f32x4 acc[4][4];
#pragma unroll
  for (int i = 0; i < 4; ++i)
#pragma unroll
    for (int j = 0; j < 4; ++j) acc[i][j] = (f32x4)0.f;

  const int fr = l & 15;
  const int kg = (l >> 4) * 8;

  for (int k0 = 0; k0 < DD; k0 += 32) {
    __syncthreads();
#pragma unroll
    for (int c = 0; c < 2; ++c) {
      int e = (w * 2 + c) * 512 + l * 8;
      int row = e >> 5, kk = e & 31;
      async_copy16(A + (size_t)(bm + row) * DD + k0 + kk, As + (w * 2 + c) * 512);
      async_copy16(BT + (size_t)(bn + row) * DD + k0 + kk, Bs + (w * 2 + c) * 512);
    }
    __syncthreads();

    bf16x8 af[4], bfr[4];
#pragma unroll
    for (int i = 0; i < 4; ++i)
      af[i] = *(const bf16x8*)(As + (wm + i * 16 + fr) * 32 + kg);
#pragma unroll
    for (int j = 0; j < 4; ++j)
      bfr[j] = *(const bf16x8*)(Bs + (wn + j * 16 + fr) * 32 + kg);
#pragma unroll
    for (int i = 0; i < 4; ++i)
#pragma unroll
      for (int j = 0; j < 4; ++j)
        acc[i][j] = __builtin_amdgcn_mfma_f32_16x16x32_bf16(af[i], bfr[j], acc[i][j], 0, 0, 0);
  }

  const int col_l = l & 15;
  const int row_l = (l >> 4) * 4;

  if (STORE == 2) {
    // Transpose 128x128 C tile via LDS (4 passes of 32 n-cols), then store
    // VbT[(b*HH+h)*HD+hd][s] with 256 B contiguous runs along s.
    unsigned short* out = (unsigned short*)outp;
    unsigned int* T = (unsigned int*)As;  // 2048 dwords
    const int b_ = bm >> 11;
    const int srow0 = bm & 2047;          // within-batch S offset
#pragma unroll
    for (int p = 0; p < 4; ++p) {
      __syncthreads();  // As free (K-loop done / previous pass read done)
      if ((w & 1) == (p >> 1)) {
        const int jt0 = (p & 1) * 2;
#pragma unroll
        for (int jj = 0; jj < 2; ++jj) {
          int jt = jt0 + jj;
          int n_p = jj * 16 + col_l;          // n within pass [0,32)
          float bv = bias[bn + p * 32 + n_p];
#pragma unroll
          for (int i = 0; i < 4; ++i) {
            int m0 = wm + i * 16 + row_l;     // even
#pragma unroll
            for (int pr = 0; pr < 2; ++pr) {
              unsigned int val =
                  (unsigned int)f2bf(acc[i][jt][2 * pr] + bv) |
                  ((unsigned int)f2bf(acc[i][jt][2 * pr + 1] + bv) << 16);
              int m = m0 + 2 * pr;
              T[n_p * 64 + (((m >> 1)) ^ ((n_p & 7) << 2))] = val;
            }
          }
        }
      }
      __syncthreads();
#pragma unroll
      for (int c = 0; c < 2; ++c) {
        int q = t + c * 256;
        int n_p = q >> 4, cpos = q & 15;
        uint4 v = *(const uint4*)(T + n_p * 64 + ((cpos * 4) ^ ((n_p & 7) << 2)));
        int n_glob = bn + p * 32 + n_p;
        int h_ = n_glob >> 6, hd_ = n_glob & 63;
        *(uint4*)(out + ((size_t)((b_ * HH + h_) * HD + hd_)) * SS + srow0 + cpos * 8) = v;
      }
    }
    return;
  }

#pragma unroll
  for (int i = 0; i < 4; ++i) {
    int m_base = bm + wm + i * 16 + row_l;
#pragma unroll
    for (int j = 0; j < 4; ++j) {
      int n = bn + wn + j * 16 + col_l;
      float bv = bias[n];
      if (STORE == 0) {
        float* out = (float*)outp;
#pragma unroll
        for (int r = 0; r < 4; ++r)
          out[(size_t)(m_base + r) * DD + n] = acc[i][j][r] + bv;
      } else {
        unsigned short* out = (unsigned short*)outp;
        int h_ = n >> 6, hd_ = n & 63;
#pragma unroll
        for (int r = 0; r < 4; ++r) {
          int m = m_base + r;
          int b_ = m >> 11, s_ = m & 2047;
          out[(((size_t)(b_ * HH + h_) * SS) + s_) * HD + hd_] =
              f2bf((acc[i][j][r] + bv) * scale);
        }
      }
    }
  }
}

// Fused QKV projection, 768 blocks, XCD-swizzled: all 24 (which,bn) blocks of
// one A-tile land on ONE XCD (i%8 = XCD round-robin) -> A-tile read once into
// that XCD's L2, 24x reuse; LLC A-traffic /3.
__global__ __launch_bounds__(256) void qkv_gemm_mfma(
    const unsigned short* __restrict__ A,
    const unsigned short* __restrict__ WqT, const unsigned short* __restrict__ WkT,
    const unsigned short* __restrict__ WvT,
    const float* __restrict__ bq, const float* __restrict__ bk,
    const float* __restrict__ bv,
    unsigned short* __restrict__ Qo, unsigned short* __restrict__ Ko,
    unsigned short* __restrict__ VTo) {
  const int i = blockIdx.x;
  const int xcd = i & 7;
  const int slot = i >> 3;            // 0..95
  const int bm = (xcd + 8 * (slot / 24)) * 128;
  const int c = slot % 24;
  const int which = c >> 3;
  const int bn = (c & 7) * 128;
  if (which == 0)
    gemm_core<1>(A, WqT, bq, (void*)Qo, 0.18033688011112042f, bm, bn);
  else if (which == 1)
    gemm_core<1>(A, WkT, bk, (void*)Ko, 1.0f, bm, bn);
  else
    gemm_core<2>(A, WvT, bv, (void*)VTo, 1.0f, bm, bn);
}

// output projection, 256 blocks, XCD-swizzled likewise (8 bn per bm on one XCD)
__global__ __launch_bounds__(256) void out_gemm_mfma(
    const unsigned short* __restrict__ A, const unsigned short* __restrict__ WoT,
    const float* __restrict__ bo, float* __restrict__ out) {
  const int i = blockIdx.x;
  const int xcd = i & 7;
  const int slot = i >> 3;            // 0..31
  const int bm = (xcd + 8 * (slot >> 3)) * 128;
  const int bn = (slot & 7) * 128;
  gemm_core<0>(A, WoT, bo, (void*)out, 1.0f, bm, bn);
}

// ---------------------------------------------------------------------------
// MFMA flash attention v6: v4 structure (Q-tile 128, 4 waves, dbuf K/V) but
// the P C-layout->B-layout conversion goes through a wave-private LDS scratch
// (8 ds_write_b64 + 4 ds_read_b128 per wave/iter) instead of 32 ds_bpermute
// -- R10 showed the kernel is DS-pipe bound and bpermutes were ~2/3 of it.
// P scratch layout: [q (32)][key (64)] bf16, 16B-chunk XOR-swizzled by q&7.
// ---------------------------------------------------------------------------
__global__ __launch_bounds__(256) void flash_attn_mfma(
    const unsigned short* __restrict__ Q,   // [B,H,S,HD] bf16 (pre-scaled)
    const unsigned short* __restrict__ K,   // [B,H,S,HD] bf16
    const unsigned short* __restrict__ VT,  // [B,H,HD,S] bf16
    unsigned short* __restrict__ ctx) {     // [B,S,D] bf16
  const int bh = blockIdx.x;
  const int qt = blockIdx.y;
  const int b  = bh >> 4;
  const int h  = bh & 15;
  const int t  = threadIdx.x;
  const int w  = t >> 6;   // wave 0..3
  const int l  = t & 63;
  const int g  = l >> 4;   // lane group 0..3
  const int ln = l & 15;   // q index within n-tile

  const unsigned short* Qp = Q + ((size_t)bh * SS + (size_t)qt * 128 + w * 32) * HD;
  const unsigned short* Kp = K + (size_t)bh * SS * HD;
  const unsigned short* Vp = VT + (size_t)bh * HD * SS;

  __shared__ __align__(16) unsigned short Ks[2][64 * 64];  // [key][hd], swizzled
  __shared__ __align__(16) unsigned short Vs[2][64 * 64];  // [hd][key], swizzled
  __shared__ __align__(16) unsigned short Ps[4][32 * 64];  // per-wave P scratch

  // Q as B-operand fragments: qf[nt][kb], n=ln, k = kb*32 + g*8 + j
  bf16x8 qf[2][2];
#pragma unroll
  for (int nt = 0; nt < 2; ++nt)
#pragma unroll
    for (int kb = 0; kb < 2; ++kb)
      qf[nt][kb] = *(const bf16x8*)(Qp + (nt * 16 + ln) * HD + kb * 32 + g * 8);

  f32x4 o[2][4];
#pragma unroll
  for (int nt = 0; nt < 2; ++nt)
#pragma unroll
    for (int mt = 0; mt < 4; ++mt) o[nt][mt] = (f32x4)0.f;
  float rs[2] = {0.f, 0.f};

  char* pw = (char*)&Ps[w][0];

  // staging: 512 chunks of 16 B per tile; 2 per thread for K and V each
  auto stage = [&](int kt, int half) {
#pragma unroll
    for (int j = 0; j < 2; ++j) {
      int c = (w * 2 + j) * 64 + l;
      int row = c >> 3, cc = c & 7;
      int gcc = cc ^ (row & 7);
      async_copy16(Kp + (size_t)(kt * 64 + row) * HD + gcc * 8,
                   &Ks[half][(w * 2 + j) * 512]);
      async_copy16(Vp + (size_t)row * SS + kt * 64 + gcc * 8,
                   &Vs[half][(w * 2 + j) * 512]);
    }
  };

  stage(0, 0);
  for (int kt = 0; kt < SS / 64; ++kt) {
    const int half = kt & 1;
    __syncthreads();  // drains vmcnt -> buf[half] ready; buf[half^1] free
    if (kt + 1 < SS / 64) stage(kt + 1, half ^ 1);

    // --- S^T = K Q^T : st[nt][mt][r] = S[key = mt*16+4g+r][q = nt*16+ln]
    f32x4 st[2][4];
#pragma unroll
    for (int nt = 0; nt < 2; ++nt)
#pragma unroll
      for (int mt = 0; mt < 4; ++mt) st[nt][mt] = (f32x4)0.f;
#pragma unroll
    for (int kb = 0; kb < 2; ++kb)
#pragma unroll
      for (int mt = 0; mt < 4; ++mt) {
        int row = mt * 16 + ln;
        bf16x8 ka = *(const bf16x8*)(&Ks[half][row * 64 + (((kb * 4 + g) ^ (row & 7)) * 8)]);
        st[0][mt] = __builtin_amdgcn_mfma_f32_16x16x32_bf16(ka, qf[0][kb], st[0][mt], 0, 0, 0);
        st[1][mt] = __builtin_amdgcn_mfma_f32_16x16x32_bf16(ka, qf[1][kb], st[1][mt], 0, 0, 0);
      }

    // --- p = exp2(s'); pack bf16 pairs; write P to wave-private LDS scratch
    // [q][key]: lane (g,ln) holds keys 16mt+4g..+3 for q = nt*16+ln.
    // byte addr = q*128 + chunk^  swizzle: chunk=(2mt+(g>>1))^(q&7), +8 if g odd
#pragma unroll
    for (int nt = 0; nt < 2; ++nt) {
      const int q = nt * 16 + ln;
      const int qs = q & 7;
#pragma unroll
      for (int mt = 0; mt < 4; ++mt) {
        float p0 = fast_exp2(st[nt][mt][0]);
        float p1 = fast_exp2(st[nt][mt][1]);
        float p2 = fast_exp2(st[nt][mt][2]);
        float p3 = fast_exp2(st[nt][mt][3]);
        uint2 v2;
        v2.x = __builtin_amdgcn_perm(__float_as_uint(p1), __float_as_uint(p0),
                                     0x07060302u);  // lo=p0,hi=p1
        v2.y = __builtin_amdgcn_perm(__float_as_uint(p3), __float_as_uint(p2),
                                     0x07060302u);
        rs[nt] += (p0 + p1) + (p2 + p3);
        int chunk = (2 * mt + (g >> 1)) ^ qs;
        *(uint2*)(pw + q * 128 + chunk * 16 + (g & 1) * 8) = v2;
      }
    }

    // --- O^T += V^T P^T : P B-frags read back from LDS (wave-local, no barrier)
#pragma unroll
    for (int kb = 0; kb < 2; ++kb) {
      bf16x8 pbv[2];
#pragma unroll
      for (int nt = 0; nt < 2; ++nt) {
        const int q = nt * 16 + ln;
        int chunk = (4 * kb + g) ^ (q & 7);
        pbv[nt] = *(const bf16x8*)(pw + q * 128 + chunk * 16);
      }
#pragma unroll
      for (int mt = 0; mt < 4; ++mt) {
        int row = mt * 16 + ln;
        bf16x8 va = *(const bf16x8*)(&Vs[half][row * 64 + (((kb * 4 + g) ^ (row & 7)) * 8)]);
        o[0][mt] = __builtin_amdgcn_mfma_f32_16x16x32_bf16(va, pbv[0], o[0][mt], 0, 0, 0);
        o[1][mt] = __builtin_amdgcn_mfma_f32_16x16x32_bf16(va, pbv[1], o[1][mt], 0, 0, 0);
      }
    }
  }

  // --- epilogue: reduce l over lane groups, normalize, store bf16 ctx
#pragma unroll
  for (int nt = 0; nt < 2; ++nt) {
    float lsum = rs[nt];
    lsum += __shfl_xor(lsum, 16, 64);
    lsum += __shfl_xor(lsum, 32, 64);
    float inv = 1.f / lsum;
    int srow = qt * 128 + w * 32 + nt * 16 + ln;
    unsigned short* cb = ctx + (size_t)(b * SS + srow) * DD + h * HD;
#pragma unroll
    for (int mt = 0; mt < 4; ++mt) {
      ushort4 u4;
      u4.x = f2bf(o[nt][mt][0] * inv);
      u4.y = f2bf(o[nt][mt][1] * inv);
      u4.z = f2bf(o[nt][mt][2] * inv);
      u4.w = f2bf(o[nt][mt][3] * inv);
      *(ushort4*)(cb + mt * 16 + 4 * g) = u4;
    }
  }
}

// ---------------------------------------------------------------------------
extern "C" void kernel_launch(void* const* d_in, const int* in_sizes, int n_in,
                              void* d_out, int out_size, void* d_ws, size_t ws_size,
                              hipStream_t stream) {
  const float* x  = (const float*)d_in[0];
  const float* Wq = (const float*)d_in[1];
  const float* bq = (const float*)d_in[2];
  const float* Wk = (const float*)d_in[3];
  const float* bk = (const float*)d_in[4];
  const float* Wv = (const float*)d_in[5];
  const float* bv = (const float*)d_in[6];
  const float* Wo = (const float*)d_in[7];
  const float* bo = (const float*)d_in[8];
  float* out = (float*)d_out;

  const size_t ELEMS = (size_t)BB * SS * DD;  // 4,194,304
  char* ws = (char*)d_ws;
  unsigned short* xb   = (unsigned short*)ws;  ws += ELEMS * 2;
  unsigned short* WqT  = (unsigned short*)ws;  ws += (size_t)DD * DD * 2;
  unsigned short* WkT  = (unsigned short*)ws;  ws += (size_t)DD * DD * 2;
  unsigned short* WvT  = (unsigned short*)ws;  ws += (size_t)DD * DD * 2;
  unsigned short* WoT  = (unsigned short*)ws;  ws += (size_t)DD * DD * 2;
  unsigned short* Qb   = (unsigned short*)ws;  ws += ELEMS * 2;
  unsigned short* Kb   = (unsigned short*)ws;  ws += ELEMS * 2;
  unsigned short* VbT  = (unsigned short*)ws;  ws += ELEMS * 2;
  unsigned short* ctxb = (unsigned short*)ws;  ws += ELEMS * 2;

  // fused prep: x->bf16 (4096 blocks) + 4 weight transposes (4096 blocks)
  prep_kernel<<<8192, 256, 0, stream>>>(x, xb, Wq, WqT, Wk, WkT, Wv, WvT, Wo, WoT);

  qkv_gemm_mfma<<<768, 256, 0, stream>>>(xb, WqT, WkT, WvT, bq, bk, bv,
                                         Qb, Kb, VbT);

  dim3 attn_grid(BB * HH, SS / 128);           // (32, 16) = 512 blocks
  flash_attn_mfma<<<attn_grid, 256, 0, stream>>>(Qb, Kb, VbT, ctxb);

  out_gemm_mfma<<<256, 256, 0, stream>>>(ctxb, WoT, bo, out);
}